// Round 14
// baseline (239.763 us; speedup 1.0000x reference)
//
#include <hip/hip_runtime.h>

// MultiplicativeAttention: B=8, QL=SL=2048, QD=SD=OD=512
//   qw = q@w; scores = qw@s^T (mask -> -1e10); attn_w = softmax(scores);
//   attn_out = (attn_w @ s) @ out_w^T + out_b
// Outputs (fp32, concat): attn_w [8*2048*2048], attn_out [8*2048*512]
//
// R14 = R13 with the staging swizzle bug fixed: sTs is pre-swizzled in
// GLOBAL memory, so the gload_lds source column must be LINEAR (the R13
// source-XOR un-did the pre-swizzle while the read XOR remained -> wrong
// B operand, attn_out failed). Rule #21: swizzle exactly once per side.

#define NEG_FILL -60000.0f  // fp16-exact mask fill; exp(NEG_FILL - m) == 0

#define AS1 __attribute__((address_space(1)))
#define AS3 __attribute__((address_space(3)))

typedef __attribute__((ext_vector_type(8))) short short8;   // 8 bf16/fp16
typedef __attribute__((ext_vector_type(4))) float floatx4;  // MFMA acc
typedef __attribute__((ext_vector_type(2))) float floatx2;
typedef __attribute__((ext_vector_type(2))) short short2e;  // 2 fp16

__device__ __forceinline__ unsigned short f2u(float x) {  // f32 -> bf16 RNE
  unsigned int u = __float_as_uint(x);
  unsigned int r = (u + 0x7fffu + ((u >> 16) & 1u)) >> 16;
  return (unsigned short)r;
}
__device__ __forceinline__ unsigned short f2h(float x) {  // f32 -> fp16 bits
  _Float16 h = (_Float16)x;
  return __builtin_bit_cast(unsigned short, h);
}
__device__ __forceinline__ float h2f(unsigned short u) {  // fp16 bits -> f32
  _Float16 h = __builtin_bit_cast(_Float16, u);
  return (float)h;
}

// ---------------------------------------------------------------------------
// cast fp32 [R][C] -> bf16 copy (dN) and/or transpose (dT); SWT is the XOR
// row-mask baked into dT's layout: dT[d][k ^ ((d & SWT) << 3)] = src[k][d]
template <int SWT>
__global__ void cast_nt(const float* __restrict__ src,
                        unsigned short* __restrict__ dN,
                        unsigned short* __restrict__ dT, int R, int C) {
  __shared__ unsigned short t[32][33];
  const int b = blockIdx.z;
  const size_t boff = (size_t)b * R * C;
  const int r0 = blockIdx.y * 32, c0 = blockIdx.x * 32;
  const int tx = threadIdx.x;
  for (int i = threadIdx.y; i < 32; i += 8) {
    unsigned short u = f2u(src[boff + (size_t)(r0 + i) * C + c0 + tx]);
    t[i][tx] = u;
    if (dN) dN[boff + (size_t)(r0 + i) * C + c0 + tx] = u;
  }
  __syncthreads();
  if (dT)
    for (int i = threadIdx.y; i < 32; i += 8) {
      int d = c0 + i;  // dT row
      int k = (r0 + tx) ^ ((d & SWT) << 3);
      dT[boff + (size_t)d * R + k] = t[tx][i];
    }
}

// ---------------------------------------------------------------------------
// Generic GEMM: C[m][n] = sum_k A[m][k]*Bt[n][k]. 128x128 tile, BK=32, 4 waves.
// AF32: A fp32 reg-staged; else bf16 via global_load_lds.
// OUT_MODE: 0 = bf16 linear out; 2 = fp32 + bias
template <int AF32, int OUT_MODE>
__global__ __launch_bounds__(256) void gemm_bt(
    const void* __restrict__ A_, const unsigned short* __restrict__ Bt_,
    void* __restrict__ C_, const float* __restrict__ bias, int N, int K) {
  __shared__ unsigned short As[128 * 32];
  __shared__ unsigned short Bs[128 * 32];

  const int tid = threadIdx.x;
  const int lane = tid & 63, wave = tid >> 6;
  const int wr = wave >> 1, wc = wave & 1;
  const int l16 = lane & 15, lh = lane >> 4;
  const int m0 = blockIdx.y * 128, n0 = blockIdx.x * 128;
  const unsigned short* Bt = Bt_;

  floatx4 acc[4][4] = {};

  for (int k0 = 0; k0 < K; k0 += 32) {
    float4 av[4];
    if constexpr (AF32) {
      const float* A = (const float*)A_;
#pragma unroll
      for (int i = 0; i < 4; ++i) {
        int e = (i * 256 + tid) * 4;
        int row = e >> 5, kk = e & 31;
        av[i] = *(const float4*)(A + (size_t)(m0 + row) * K + k0 + kk);
      }
    }
    __syncthreads();
    if constexpr (AF32) {
#pragma unroll
      for (int i = 0; i < 4; ++i) {
        int e = (i * 256 + tid) * 4;
        unsigned short b4[4] = {f2u(av[i].x), f2u(av[i].y), f2u(av[i].z), f2u(av[i].w)};
        *(uint2*)&As[e] = *(uint2*)b4;
      }
    } else {
      const unsigned short* A = (const unsigned short*)A_;
#pragma unroll
      for (int i = 0; i < 2; ++i) {
        int chunk = i * 4 + wave;
        int e = chunk * 512 + lane * 8;
        int row = e >> 5, kk = e & 31;
        __builtin_amdgcn_global_load_lds(
            (const AS1 void*)(A + (size_t)(m0 + row) * K + k0 + kk),
            (AS3 void*)(As + chunk * 512), 16, 0, 0);
      }
    }
#pragma unroll
    for (int i = 0; i < 2; ++i) {
      int chunk = i * 4 + wave;
      int e = chunk * 512 + lane * 8;
      int row = e >> 5, kk = e & 31;
      __builtin_amdgcn_global_load_lds(
          (const AS1 void*)(Bt + (size_t)(n0 + row) * K + k0 + kk),
          (AS3 void*)(Bs + chunk * 512), 16, 0, 0);
    }
    __syncthreads();

    short8 af[4], bfr[4];
#pragma unroll
    for (int m = 0; m < 4; ++m)
      af[m] = *(const short8*)&As[(wr * 64 + m * 16 + l16) * 32 + lh * 8];
#pragma unroll
    for (int n = 0; n < 4; ++n)
      bfr[n] = *(const short8*)&Bs[(wc * 64 + n * 16 + l16) * 32 + lh * 8];
#pragma unroll
    for (int m = 0; m < 4; ++m)
#pragma unroll
      for (int n = 0; n < 4; ++n)
        acc[m][n] = __builtin_amdgcn_mfma_f32_16x16x32_bf16(af[m], bfr[n], acc[m][n], 0, 0, 0);
  }

  const int rbase = m0 + wr * 64, cbase = n0 + wc * 64;
  if constexpr (OUT_MODE == 0) {
    unsigned short* C = (unsigned short*)C_;
#pragma unroll
    for (int m = 0; m < 4; ++m)
#pragma unroll
      for (int n = 0; n < 4; ++n) {
        int row = rbase + m * 16 + lh * 4;
        int col = cbase + n * 16 + l16;
#pragma unroll
        for (int j = 0; j < 4; ++j)
          C[(size_t)(row + j) * N + col] = f2u(acc[m][n][j]);
      }
  } else {
    float* C = (float*)C_;
#pragma unroll
    for (int n = 0; n < 4; ++n) {
      int col = cbase + n * 16 + l16;
      float bv = bias[col];
#pragma unroll
      for (int m = 0; m < 4; ++m) {
        int row = rbase + m * 16 + lh * 4;
#pragma unroll
        for (int j = 0; j < 4; ++j)
          C[(size_t)(row + j) * N + col] = acc[m][n][j] + bv;
      }
    }
  }
}

// ---------------------------------------------------------------------------
// Scores + mask + partial softmax stats. 128x128 tile, BK=32, 4 waves.
// K-loop: TRIPLE-buffered As/Bs, 3-deep prefetch, counted vmcnt(8).
// Raw masked scores -> fp16 packed into attn_w fp32 row slots + partial
// (max,sumexp) -> statp.  (identical to R12)
__global__ __launch_bounds__(256) void gemm_sc(
    const unsigned short* __restrict__ qw,   // [16384][512] bf16
    const unsigned short* __restrict__ sN,   // [8][2048][512] bf16
    const int* __restrict__ maskg,           // [8][2048]
    float* __restrict__ attw,                // [16384][2048] fp32 slots
    float2* __restrict__ statp) {            // [16384][32]
  __shared__ unsigned short As[3][128 * 32];  // 3 x 8 KB
  __shared__ unsigned short Bs[3][128 * 32];  // 3 x 8 KB -> 48 KB total

  const int tid = threadIdx.x;
  const int lane = tid & 63, wave = tid >> 6;
  const int wr = wave >> 1, wc = wave & 1;
  const int l16 = lane & 15, lh = lane >> 4;
  const int z = blockIdx.z;
  const int m0 = blockIdx.y * 128, n0 = blockIdx.x * 128;
  const unsigned short* Ab = qw + ((size_t)z * 2048 + m0) * 512;
  const unsigned short* Bb = sN + ((size_t)z * 2048 + n0) * 512;

  const int chunk0 = wave, chunk1 = 4 + wave;
  const int e0 = chunk0 * 512 + lane * 8, e1 = chunk1 * 512 + lane * 8;
  const int row0 = e0 >> 5, kk0 = e0 & 31;
  const int row1 = e1 >> 5, kk1 = e1 & 31;

#define STAGE_SC(t, buf)                                                      \
  {                                                                           \
    const int k0_ = (t) * 32;                                                 \
    __builtin_amdgcn_global_load_lds(                                         \
        (const AS1 void*)(Ab + (size_t)row0 * 512 + k0_ + kk0),               \
        (AS3 void*)(&As[buf][chunk0 * 512]), 16, 0, 0);                       \
    __builtin_amdgcn_global_load_lds(                                         \
        (const AS1 void*)(Bb + (size_t)row0 * 512 + k0_ + kk0),               \
        (AS3 void*)(&Bs[buf][chunk0 * 512]), 16, 0, 0);                       \
    __builtin_amdgcn_global_load_lds(                                         \
        (const AS1 void*)(Ab + (size_t)row1 * 512 + k0_ + kk1),               \
        (AS3 void*)(&As[buf][chunk1 * 512]), 16, 0, 0);                       \
    __builtin_amdgcn_global_load_lds(                                         \
        (const AS1 void*)(Bb + (size_t)row1 * 512 + k0_ + kk1),               \
        (AS3 void*)(&Bs[buf][chunk1 * 512]), 16, 0, 0);                       \
  }

  floatx4 acc[4][4] = {};

  STAGE_SC(0, 0);
  STAGE_SC(1, 1);
  for (int t = 0; t < 16; ++t) {
    const int cur = t % 3;
    if (t + 2 < 16) STAGE_SC(t + 2, (t + 2) % 3);
    __builtin_amdgcn_sched_barrier(0);
    if (t + 2 < 16)
      asm volatile("s_waitcnt vmcnt(8)" ::: "memory");
    else if (t + 1 < 16)
      asm volatile("s_waitcnt vmcnt(4)" ::: "memory");
    else
      asm volatile("s_waitcnt vmcnt(0)" ::: "memory");
    __builtin_amdgcn_s_barrier();
    __builtin_amdgcn_sched_barrier(0);

    short8 af[4], bfr[4];
#pragma unroll
    for (int m = 0; m < 4; ++m)
      af[m] = *(const short8*)&As[cur][(wr * 64 + m * 16 + l16) * 32 + lh * 8];
#pragma unroll
    for (int n = 0; n < 4; ++n)
      bfr[n] = *(const short8*)&Bs[cur][(wc * 64 + n * 16 + l16) * 32 + lh * 8];
#pragma unroll
    for (int m = 0; m < 4; ++m)
#pragma unroll
      for (int n = 0; n < 4; ++n)
        acc[m][n] = __builtin_amdgcn_mfma_f32_16x16x32_bf16(af[m], bfr[n], acc[m][n], 0, 0, 0);

    asm volatile("s_waitcnt lgkmcnt(0)" ::: "memory");
    __builtin_amdgcn_sched_barrier(0);
    __builtin_amdgcn_s_barrier();
  }
#undef STAGE_SC

  bool keep[4];
#pragma unroll
  for (int n = 0; n < 4; ++n)
    keep[n] = maskg[z * 2048 + n0 + wc * 64 + n * 16 + l16] != 0;
#pragma unroll
  for (int m = 0; m < 4; ++m)
#pragma unroll
    for (int n = 0; n < 4; ++n)
      if (!keep[n]) {
        floatx4 f = {NEG_FILL, NEG_FILL, NEG_FILL, NEG_FILL};
        acc[m][n] = f;
      }

#pragma unroll
  for (int m = 0; m < 4; ++m)
#pragma unroll
    for (int j = 0; j < 4; ++j) {
      const int lrow = m0 + wr * 64 + m * 16 + lh * 4 + j;
      const size_t grow = (size_t)z * 2048 + lrow;
      unsigned short* rawrow = (unsigned short*)(attw + grow * 2048);
#pragma unroll
      for (int n = 0; n < 4; ++n)
        rawrow[n0 + wc * 64 + n * 16 + l16] = f2h(acc[m][n][j]);
      float tm = fmaxf(fmaxf(acc[m][0][j], acc[m][1][j]),
                       fmaxf(acc[m][2][j], acc[m][3][j]));
#pragma unroll
      for (int o = 1; o < 16; o <<= 1) tm = fmaxf(tm, __shfl_xor(tm, o));
      float es = __expf(acc[m][0][j] - tm) + __expf(acc[m][1][j] - tm) +
                 __expf(acc[m][2][j] - tm) + __expf(acc[m][3][j] - tm);
#pragma unroll
      for (int o = 1; o < 16; o <<= 1) es += __shfl_xor(es, o);
      if (l16 == 0) {
        float2 st = {tm, es};
        statp[grow * 32 + blockIdx.x * 2 + wc] = st;
      }
    }
}

// ---------------------------------------------------------------------------
// Combine 32 partials per row -> (max, 1/sum). 16384 rows.
__global__ __launch_bounds__(256) void finalize_stats(
    const float2* __restrict__ statp, float2* __restrict__ fstat) {
  const int r = blockIdx.x * 256 + threadIdx.x;
  const float2* p = statp + (size_t)r * 32;
  float fm = -3.4e38f;
#pragma unroll
  for (int i = 0; i < 32; ++i) fm = fmaxf(fm, p[i].x);
  float fs = 0.f;
#pragma unroll
  for (int i = 0; i < 32; ++i) fs += p[i].y * __expf(p[i].x - fm);
  float2 o = {fm, 1.0f / fs};
  fstat[r] = o;
}

// ---------------------------------------------------------------------------
// Normalize + PV. Block = 32 q-rows x N=512, 8 waves (wave w owns cols
// w*64..+64), BK=32, grid 512 (= 2 blocks/CU at 68 KB LDS).
// Descending k-tiles; in-place proof: p-write of tile u clobbers raw tiles
// 2u,2u+1 >= u (already read; u=0 covered by 2-iteration register prefetch).
// Single-barrier pipeline; queue invariant at each barrier: [p-store,
// raw-prefetch] -> vmcnt(2); never a drain in the main loop.
// sTs is pre-swizzled (mask 3) in global: staging source LINEAR, read XORs.
__global__ __launch_bounds__(512) void pv_norm(
    float* __restrict__ attw,                 // rows: fp16 raw -> fp32 p
    const unsigned short* __restrict__ sTs,   // [8][512][2048] swizzled (mask 3)
    const float2* __restrict__ fstat,         // [16384] (max, 1/sum)
    unsigned short* __restrict__ pre) {       // [16384][512] bf16
  __shared__ unsigned short Bsl[2][512 * 32];  // 64 KB
  __shared__ unsigned short Pl[2][32 * 32];    // 4 KB -> 68 KB total
  const int tid = threadIdx.x, lane = tid & 63, w = tid >> 6;
  const int l16 = lane & 15, lh = lane >> 4;
  const int z = blockIdx.x & 7, ms = blockIdx.x >> 3;  // batch -> XCD pinning
  const size_t qrow0 = (size_t)z * 2048 + ms * 32;
  const unsigned short* Bz = sTs + (size_t)z * 512 * 2048;
  float* attwB = attw + qrow0 * 2048;
  const int prow = tid >> 4, pkc = (tid & 15) * 2;   // 16 thr/row, 2 cols each
  const unsigned short* rawrow = (const unsigned short*)(attwB + (size_t)prow * 2048);
  float* prowp = attwB + (size_t)prow * 2048;
  const float2 st0 = fstat[qrow0 + prow];
  const float fm = st0.x, inv = st0.y;
  // staging: 4 loads/thread; load i covers d = i*128 + (tid>>2), col (tid&3)*8.
  // Source col LINEAR: global sTs rows are pre-swizzled, so LDS content ends
  // up swizzled and the frag read deswizzles with fsw.
  const int sd = tid >> 2;
  const int scol = (tid & 3) * 8;
  const int psw = (prow & 3) << 3;
  const int fsw = (l16 & 3) << 3;

#define STAGE_PV(t, buf)                                                       \
  {                                                                            \
    _Pragma("unroll") for (int i = 0; i < 4; ++i) {                            \
      int d = i * 128 + sd;                                                    \
      __builtin_amdgcn_global_load_lds(                                        \
          (const AS1 void*)(Bz + (size_t)d * 2048 + (t) * 32 + scol),          \
          (AS3 void*)(&Bsl[buf][i * 4096 + tid * 8]), 16, 0, 0);               \
    }                                                                          \
  }

  floatx4 acc[2][4] = {};

  // ---- prologue: tile 63 -> buf 0; raw(62) prefetch in flight
  short2e rv = *(const short2e*)(rawrow + 63 * 32 + pkc);
  STAGE_PV(63, 0);
  __builtin_amdgcn_sched_barrier(0);
  {
    float p0 = __expf(h2f((unsigned short)rv[0]) - fm) * inv;
    float p1 = __expf(h2f((unsigned short)rv[1]) - fm) * inv;
    floatx2 pw = {p0, p1};
    *(floatx2*)(prowp + 63 * 32 + pkc) = pw;
    unsigned int pb = (unsigned int)f2u(p0) | ((unsigned int)f2u(p1) << 16);
    *(unsigned int*)&Pl[0][prow * 32 + (pkc ^ psw)] = pb;
  }
  short2e rvn = *(const short2e*)(rawrow + 62 * 32 + pkc);
  asm volatile("s_waitcnt lgkmcnt(0)" ::: "memory");
  asm volatile("s_waitcnt vmcnt(2)" ::: "memory");  // stage(63) done; [st,raw] left
  __builtin_amdgcn_sched_barrier(0);
  __builtin_amdgcn_s_barrier();
  __builtin_amdgcn_sched_barrier(0);

  for (int t = 63; t >= 0; --t) {
    const int cur = (63 - t) & 1, nxt = cur ^ 1;
    if (t > 0) STAGE_PV(t - 1, nxt);
    __builtin_amdgcn_sched_barrier(0);
    // frag ds_reads for tile t
    short8 af[2], bf[4];
#pragma unroll
    for (int m = 0; m < 2; ++m)
      af[m] = *(const short8*)&Pl[cur][(m * 16 + l16) * 32 + (lh * 8 ^ fsw)];
#pragma unroll
    for (int n = 0; n < 4; ++n)
      bf[n] = *(const short8*)&Bsl[cur][(w * 64 + n * 16 + l16) * 32 + (lh * 8 ^ fsw)];
    // normalize tile t-1 (overlaps MFMA window) + p store + raw(t-2) prefetch
    short2e rv2 = rvn;
    if (t > 0) {
      float p0 = __expf(h2f((unsigned short)rvn[0]) - fm) * inv;
      float p1 = __expf(h2f((unsigned short)rvn[1]) - fm) * inv;
      floatx2 pw = {p0, p1};
      *(floatx2*)(prowp + (t - 1) * 32 + pkc) = pw;
      if (t >= 2) rv2 = *(const short2e*)(rawrow + (t - 2) * 32 + pkc);
      unsigned int pb = (unsigned int)f2u(p0) | ((unsigned int)f2u(p1) << 16);
      *(unsigned int*)&Pl[nxt][prow * 32 + (pkc ^ psw)] = pb;
    }
    // MFMA on tile t
    __builtin_amdgcn_s_setprio(1);
#pragma unroll
    for (int m = 0; m < 2; ++m)
#pragma unroll
      for (int n = 0; n < 4; ++n)
        acc[m][n] = __builtin_amdgcn_mfma_f32_16x16x32_bf16(af[m], bf[n], acc[m][n], 0, 0, 0);
    __builtin_amdgcn_s_setprio(0);
    // tile end: Pl[nxt] write + frag reads drained; stage(t-1) retired.
    asm volatile("s_waitcnt lgkmcnt(0)" ::: "memory");
    if (t >= 2)
      asm volatile("s_waitcnt vmcnt(2)" ::: "memory");  // leaves [st, rv2]
    else if (t == 1)
      asm volatile("s_waitcnt vmcnt(1)" ::: "memory");  // leaves [st]
    __builtin_amdgcn_sched_barrier(0);
    if (t > 0) {
      __builtin_amdgcn_s_barrier();
      __builtin_amdgcn_sched_barrier(0);
    }
    rvn = rv2;
  }

  // epilogue: pre (bf16, linear)
  unsigned short* preB = pre + qrow0 * 512;
#pragma unroll
  for (int m = 0; m < 2; ++m)
#pragma unroll
    for (int n = 0; n < 4; ++n) {
      int row = m * 16 + lh * 4;
      int col = w * 64 + n * 16 + l16;
#pragma unroll
      for (int j = 0; j < 4; ++j)
        preB[(size_t)(row + j) * 512 + col] = f2u(acc[m][n][j]);
    }
#undef STAGE_PV
}

// ---------------------------------------------------------------------------
extern "C" void kernel_launch(void* const* d_in, const int* in_sizes, int n_in,
                              void* d_out, int out_size, void* d_ws, size_t ws_size,
                              hipStream_t stream) {
  const float* q = (const float*)d_in[0];      // [8,2048,512]
  const float* s = (const float*)d_in[1];      // [8,2048,512]
  const int* mask = (const int*)d_in[2];       // [8,1,2048]
  const float* w = (const float*)d_in[3];      // [512,512]
  const float* out_w = (const float*)d_in[4];  // [512,512]
  const float* out_b = (const float*)d_in[5];  // [512]

  float* attn_w = (float*)d_out;                              // [8,2048,2048]
  float* attn_out = (float*)d_out + (size_t)8 * 2048 * 2048;  // [8,2048,512]

  char* ws = (char*)d_ws;
  const size_t MB = 1024 * 1024;
  unsigned short* qw  = (unsigned short*)(ws);            // [16384,512] bf16
  unsigned short* sN  = (unsigned short*)(ws + 17 * MB);  // [8,2048,512] bf16
  unsigned short* sTs = (unsigned short*)(ws + 34 * MB);  // [8,512,2048] swz3
  unsigned short* pre = (unsigned short*)(ws + 51 * MB);  // [16384,512] bf16
  float2* statp       = (float2*)(ws + 51 * MB);          // [16384,32] (overlays pre)
  unsigned short* wT  = (unsigned short*)(ws + 68 * MB);  // [512,512] w^T
  unsigned short* owN = (unsigned short*)(ws + 68 * MB + 512 * 1024);
  float2* fstat       = (float2*)(ws + 69 * MB);          // [16384]

  dim3 tb(32, 8);
  cast_nt<3><<<dim3(16, 64, 8), tb, 0, stream>>>(s, sN, sTs, 2048, 512);
  cast_nt<0><<<dim3(16, 16, 1), tb, 0, stream>>>(w, nullptr, wT, 512, 512);
  cast_nt<0><<<dim3(16, 16, 1), tb, 0, stream>>>(out_w, owN, nullptr, 512, 512);

  // GEMM1: qw = q @ w (bf16 linear)
  gemm_bt<1, 0><<<dim3(4, 128, 1), 256, 0, stream>>>(q, wT, qw, nullptr, 512, 512);

  // scores + mask + partial stats; raw fp16 packed into attn_w rows
  gemm_sc<<<dim3(16, 16, 8), 256, 0, stream>>>(qw, sN, mask, attn_w, statp);

  // stats combine
  finalize_stats<<<64, 256, 0, stream>>>(statp, fstat);

  // in-place normalize + PV (32-row strips, 2 blocks/CU, single-barrier)
  pv_norm<<<512, 512, 0, stream>>>(attn_w, sTs, fstat, pre);

  // GEMM4: attn_out = pre @ out_w^T + out_b
  gemm_bt<0, 2><<<dim3(4, 128, 1), 256, 0, stream>>>(pre, owN, attn_out, out_b, 512, 512);

  (void)in_sizes; (void)n_in; (void)out_size; (void)ws_size;
}

// Round 15
// 231.823 us; speedup vs baseline: 1.0342x; 1.0342x over previous
//
#include <hip/hip_runtime.h>

// MultiplicativeAttention: B=8, QL=SL=2048, QD=SD=OD=512
//   qw = q@w; scores = qw@s^T (mask -> -1e10); attn_w = softmax(scores);
//   attn_out = (attn_w @ s) @ out_w^T + out_b
// Outputs (fp32, concat): attn_w [8*2048*2048], attn_out [8*2048*512]
//
// R14 = R13 with the staging swizzle bug fixed: sTs is pre-swizzled in
// GLOBAL memory, so the gload_lds source column must be LINEAR (the R13
// source-XOR un-did the pre-swizzle while the read XOR remained -> wrong
// B operand, attn_out failed). Rule #21: swizzle exactly once per side.

#define NEG_FILL -60000.0f  // fp16-exact mask fill; exp(NEG_FILL - m) == 0

#define AS1 __attribute__((address_space(1)))
#define AS3 __attribute__((address_space(3)))

typedef __attribute__((ext_vector_type(8))) short short8;   // 8 bf16/fp16
typedef __attribute__((ext_vector_type(4))) float floatx4;  // MFMA acc
typedef __attribute__((ext_vector_type(2))) float floatx2;
typedef __attribute__((ext_vector_type(2))) short short2e;  // 2 fp16

__device__ __forceinline__ unsigned short f2u(float x) {  // f32 -> bf16 RNE
  unsigned int u = __float_as_uint(x);
  unsigned int r = (u + 0x7fffu + ((u >> 16) & 1u)) >> 16;
  return (unsigned short)r;
}
__device__ __forceinline__ unsigned short f2h(float x) {  // f32 -> fp16 bits
  _Float16 h = (_Float16)x;
  return __builtin_bit_cast(unsigned short, h);
}
__device__ __forceinline__ float h2f(unsigned short u) {  // fp16 bits -> f32
  _Float16 h = __builtin_bit_cast(_Float16, u);
  return (float)h;
}

// ---------------------------------------------------------------------------
// cast fp32 [R][C] -> bf16 copy (dN) and/or transpose (dT); SWT is the XOR
// row-mask baked into dT's layout: dT[d][k ^ ((d & SWT) << 3)] = src[k][d]
template <int SWT>
__global__ void cast_nt(const float* __restrict__ src,
                        unsigned short* __restrict__ dN,
                        unsigned short* __restrict__ dT, int R, int C) {
  __shared__ unsigned short t[32][33];
  const int b = blockIdx.z;
  const size_t boff = (size_t)b * R * C;
  const int r0 = blockIdx.y * 32, c0 = blockIdx.x * 32;
  const int tx = threadIdx.x;
  for (int i = threadIdx.y; i < 32; i += 8) {
    unsigned short u = f2u(src[boff + (size_t)(r0 + i) * C + c0 + tx]);
    t[i][tx] = u;
    if (dN) dN[boff + (size_t)(r0 + i) * C + c0 + tx] = u;
  }
  __syncthreads();
  if (dT)
    for (int i = threadIdx.y; i < 32; i += 8) {
      int d = c0 + i;  // dT row
      int k = (r0 + tx) ^ ((d & SWT) << 3);
      dT[boff + (size_t)d * R + k] = t[tx][i];
    }
}

// ---------------------------------------------------------------------------
// Generic GEMM: C[m][n] = sum_k A[m][k]*Bt[n][k]. 128x128 tile, BK=32, 4 waves.
// AF32: A fp32 reg-staged; else bf16 via global_load_lds.
// OUT_MODE: 0 = bf16 linear out; 2 = fp32 + bias
template <int AF32, int OUT_MODE>
__global__ __launch_bounds__(256) void gemm_bt(
    const void* __restrict__ A_, const unsigned short* __restrict__ Bt_,
    void* __restrict__ C_, const float* __restrict__ bias, int N, int K) {
  __shared__ unsigned short As[128 * 32];
  __shared__ unsigned short Bs[128 * 32];

  const int tid = threadIdx.x;
  const int lane = tid & 63, wave = tid >> 6;
  const int wr = wave >> 1, wc = wave & 1;
  const int l16 = lane & 15, lh = lane >> 4;
  const int m0 = blockIdx.y * 128, n0 = blockIdx.x * 128;
  const unsigned short* Bt = Bt_;

  floatx4 acc[4][4] = {};

  for (int k0 = 0; k0 < K; k0 += 32) {
    float4 av[4];
    if constexpr (AF32) {
      const float* A = (const float*)A_;
#pragma unroll
      for (int i = 0; i < 4; ++i) {
        int e = (i * 256 + tid) * 4;
        int row = e >> 5, kk = e & 31;
        av[i] = *(const float4*)(A + (size_t)(m0 + row) * K + k0 + kk);
      }
    }
    __syncthreads();
    if constexpr (AF32) {
#pragma unroll
      for (int i = 0; i < 4; ++i) {
        int e = (i * 256 + tid) * 4;
        unsigned short b4[4] = {f2u(av[i].x), f2u(av[i].y), f2u(av[i].z), f2u(av[i].w)};
        *(uint2*)&As[e] = *(uint2*)b4;
      }
    } else {
      const unsigned short* A = (const unsigned short*)A_;
#pragma unroll
      for (int i = 0; i < 2; ++i) {
        int chunk = i * 4 + wave;
        int e = chunk * 512 + lane * 8;
        int row = e >> 5, kk = e & 31;
        __builtin_amdgcn_global_load_lds(
            (const AS1 void*)(A + (size_t)(m0 + row) * K + k0 + kk),
            (AS3 void*)(As + chunk * 512), 16, 0, 0);
      }
    }
#pragma unroll
    for (int i = 0; i < 2; ++i) {
      int chunk = i * 4 + wave;
      int e = chunk * 512 + lane * 8;
      int row = e >> 5, kk = e & 31;
      __builtin_amdgcn_global_load_lds(
          (const AS1 void*)(Bt + (size_t)(n0 + row) * K + k0 + kk),
          (AS3 void*)(Bs + chunk * 512), 16, 0, 0);
    }
    __syncthreads();

    short8 af[4], bfr[4];
#pragma unroll
    for (int m = 0; m < 4; ++m)
      af[m] = *(const short8*)&As[(wr * 64 + m * 16 + l16) * 32 + lh * 8];
#pragma unroll
    for (int n = 0; n < 4; ++n)
      bfr[n] = *(const short8*)&Bs[(wc * 64 + n * 16 + l16) * 32 + lh * 8];
#pragma unroll
    for (int m = 0; m < 4; ++m)
#pragma unroll
      for (int n = 0; n < 4; ++n)
        acc[m][n] = __builtin_amdgcn_mfma_f32_16x16x32_bf16(af[m], bfr[n], acc[m][n], 0, 0, 0);
  }

  const int rbase = m0 + wr * 64, cbase = n0 + wc * 64;
  if constexpr (OUT_MODE == 0) {
    unsigned short* C = (unsigned short*)C_;
#pragma unroll
    for (int m = 0; m < 4; ++m)
#pragma unroll
      for (int n = 0; n < 4; ++n) {
        int row = rbase + m * 16 + lh * 4;
        int col = cbase + n * 16 + l16;
#pragma unroll
        for (int j = 0; j < 4; ++j)
          C[(size_t)(row + j) * N + col] = f2u(acc[m][n][j]);
      }
  } else {
    float* C = (float*)C_;
#pragma unroll
    for (int n = 0; n < 4; ++n) {
      int col = cbase + n * 16 + l16;
      float bv = bias[col];
#pragma unroll
      for (int m = 0; m < 4; ++m) {
        int row = rbase + m * 16 + lh * 4;
#pragma unroll
        for (int j = 0; j < 4; ++j)
          C[(size_t)(row + j) * N + col] = acc[m][n][j] + bv;
      }
    }
  }
}

// ---------------------------------------------------------------------------
// Scores + mask + partial softmax stats. 128x128 tile, BK=32, 4 waves.
// K-loop: TRIPLE-buffered As/Bs, 3-deep prefetch, counted vmcnt(8).
// Raw masked scores -> fp16 packed into attn_w fp32 row slots + partial
// (max,sumexp) -> statp.  (identical to R12)
__global__ __launch_bounds__(256) void gemm_sc(
    const unsigned short* __restrict__ qw,   // [16384][512] bf16
    const unsigned short* __restrict__ sN,   // [8][2048][512] bf16
    const int* __restrict__ maskg,           // [8][2048]
    float* __restrict__ attw,                // [16384][2048] fp32 slots
    float2* __restrict__ statp) {            // [16384][32]
  __shared__ unsigned short As[3][128 * 32];  // 3 x 8 KB
  __shared__ unsigned short Bs[3][128 * 32];  // 3 x 8 KB -> 48 KB total

  const int tid = threadIdx.x;
  const int lane = tid & 63, wave = tid >> 6;
  const int wr = wave >> 1, wc = wave & 1;
  const int l16 = lane & 15, lh = lane >> 4;
  const int z = blockIdx.z;
  const int m0 = blockIdx.y * 128, n0 = blockIdx.x * 128;
  const unsigned short* Ab = qw + ((size_t)z * 2048 + m0) * 512;
  const unsigned short* Bb = sN + ((size_t)z * 2048 + n0) * 512;

  const int chunk0 = wave, chunk1 = 4 + wave;
  const int e0 = chunk0 * 512 + lane * 8, e1 = chunk1 * 512 + lane * 8;
  const int row0 = e0 >> 5, kk0 = e0 & 31;
  const int row1 = e1 >> 5, kk1 = e1 & 31;

#define STAGE_SC(t, buf)                                                      \
  {                                                                           \
    const int k0_ = (t) * 32;                                                 \
    __builtin_amdgcn_global_load_lds(                                         \
        (const AS1 void*)(Ab + (size_t)row0 * 512 + k0_ + kk0),               \
        (AS3 void*)(&As[buf][chunk0 * 512]), 16, 0, 0);                       \
    __builtin_amdgcn_global_load_lds(                                         \
        (const AS1 void*)(Bb + (size_t)row0 * 512 + k0_ + kk0),               \
        (AS3 void*)(&Bs[buf][chunk0 * 512]), 16, 0, 0);                       \
    __builtin_amdgcn_global_load_lds(                                         \
        (const AS1 void*)(Ab + (size_t)row1 * 512 + k0_ + kk1),               \
        (AS3 void*)(&As[buf][chunk1 * 512]), 16, 0, 0);                       \
    __builtin_amdgcn_global_load_lds(                                         \
        (const AS1 void*)(Bb + (size_t)row1 * 512 + k0_ + kk1),               \
        (AS3 void*)(&Bs[buf][chunk1 * 512]), 16, 0, 0);                       \
  }

  floatx4 acc[4][4] = {};

  STAGE_SC(0, 0);
  STAGE_SC(1, 1);
  for (int t = 0; t < 16; ++t) {
    const int cur = t % 3;
    if (t + 2 < 16) STAGE_SC(t + 2, (t + 2) % 3);
    __builtin_amdgcn_sched_barrier(0);
    if (t + 2 < 16)
      asm volatile("s_waitcnt vmcnt(8)" ::: "memory");
    else if (t + 1 < 16)
      asm volatile("s_waitcnt vmcnt(4)" ::: "memory");
    else
      asm volatile("s_waitcnt vmcnt(0)" ::: "memory");
    __builtin_amdgcn_s_barrier();
    __builtin_amdgcn_sched_barrier(0);

    short8 af[4], bfr[4];
#pragma unroll
    for (int m = 0; m < 4; ++m)
      af[m] = *(const short8*)&As[cur][(wr * 64 + m * 16 + l16) * 32 + lh * 8];
#pragma unroll
    for (int n = 0; n < 4; ++n)
      bfr[n] = *(const short8*)&Bs[cur][(wc * 64 + n * 16 + l16) * 32 + lh * 8];
#pragma unroll
    for (int m = 0; m < 4; ++m)
#pragma unroll
      for (int n = 0; n < 4; ++n)
        acc[m][n] = __builtin_amdgcn_mfma_f32_16x16x32_bf16(af[m], bfr[n], acc[m][n], 0, 0, 0);

    asm volatile("s_waitcnt lgkmcnt(0)" ::: "memory");
    __builtin_amdgcn_sched_barrier(0);
    __builtin_amdgcn_s_barrier();
  }
#undef STAGE_SC

  bool keep[4];
#pragma unroll
  for (int n = 0; n < 4; ++n)
    keep[n] = maskg[z * 2048 + n0 + wc * 64 + n * 16 + l16] != 0;
#pragma unroll
  for (int m = 0; m < 4; ++m)
#pragma unroll
    for (int n = 0; n < 4; ++n)
      if (!keep[n]) {
        floatx4 f = {NEG_FILL, NEG_FILL, NEG_FILL, NEG_FILL};
        acc[m][n] = f;
      }

#pragma unroll
  for (int m = 0; m < 4; ++m)
#pragma unroll
    for (int j = 0; j < 4; ++j) {
      const int lrow = m0 + wr * 64 + m * 16 + lh * 4 + j;
      const size_t grow = (size_t)z * 2048 + lrow;
      unsigned short* rawrow = (unsigned short*)(attw + grow * 2048);
#pragma unroll
      for (int n = 0; n < 4; ++n)
        rawrow[n0 + wc * 64 + n * 16 + l16] = f2h(acc[m][n][j]);
      float tm = fmaxf(fmaxf(acc[m][0][j], acc[m][1][j]),
                       fmaxf(acc[m][2][j], acc[m][3][j]));
#pragma unroll
      for (int o = 1; o < 16; o <<= 1) tm = fmaxf(tm, __shfl_xor(tm, o));
      float es = __expf(acc[m][0][j] - tm) + __expf(acc[m][1][j] - tm) +
                 __expf(acc[m][2][j] - tm) + __expf(acc[m][3][j] - tm);
#pragma unroll
      for (int o = 1; o < 16; o <<= 1) es += __shfl_xor(es, o);
      if (l16 == 0) {
        float2 st = {tm, es};
        statp[grow * 32 + blockIdx.x * 2 + wc] = st;
      }
    }
}

// ---------------------------------------------------------------------------
// Combine 32 partials per row -> (max, 1/sum). 16384 rows.
__global__ __launch_bounds__(256) void finalize_stats(
    const float2* __restrict__ statp, float2* __restrict__ fstat) {
  const int r = blockIdx.x * 256 + threadIdx.x;
  const float2* p = statp + (size_t)r * 32;
  float fm = -3.4e38f;
#pragma unroll
  for (int i = 0; i < 32; ++i) fm = fmaxf(fm, p[i].x);
  float fs = 0.f;
#pragma unroll
  for (int i = 0; i < 32; ++i) fs += p[i].y * __expf(p[i].x - fm);
  float2 o = {fm, 1.0f / fs};
  fstat[r] = o;
}

// ---------------------------------------------------------------------------
// Normalize + PV. Block = 32 q-rows x N=512, 8 waves (wave w owns cols
// w*64..+64), BK=32, grid 512 (= 2 blocks/CU at 68 KB LDS).
// Descending k-tiles; in-place proof: p-write of tile u clobbers raw tiles
// 2u,2u+1 >= u (already read; u=0 covered by 2-iteration register prefetch).
// Single-barrier pipeline; queue invariant at each barrier: [p-store,
// raw-prefetch] -> vmcnt(2); never a drain in the main loop.
// sTs is pre-swizzled (mask 3) in global: staging source LINEAR, read XORs.
__global__ __launch_bounds__(512) void pv_norm(
    float* __restrict__ attw,                 // rows: fp16 raw -> fp32 p
    const unsigned short* __restrict__ sTs,   // [8][512][2048] swizzled (mask 3)
    const float2* __restrict__ fstat,         // [16384] (max, 1/sum)
    unsigned short* __restrict__ pre) {       // [16384][512] bf16
  __shared__ unsigned short Bsl[2][512 * 32];  // 64 KB
  __shared__ unsigned short Pl[2][32 * 32];    // 4 KB -> 68 KB total
  const int tid = threadIdx.x, lane = tid & 63, w = tid >> 6;
  const int l16 = lane & 15, lh = lane >> 4;
  const int z = blockIdx.x & 7, ms = blockIdx.x >> 3;  // batch -> XCD pinning
  const size_t qrow0 = (size_t)z * 2048 + ms * 32;
  const unsigned short* Bz = sTs + (size_t)z * 512 * 2048;
  float* attwB = attw + qrow0 * 2048;
  const int prow = tid >> 4, pkc = (tid & 15) * 2;   // 16 thr/row, 2 cols each
  const unsigned short* rawrow = (const unsigned short*)(attwB + (size_t)prow * 2048);
  float* prowp = attwB + (size_t)prow * 2048;
  const float2 st0 = fstat[qrow0 + prow];
  const float fm = st0.x, inv = st0.y;
  // staging: 4 loads/thread; load i covers d = i*128 + (tid>>2), col (tid&3)*8.
  // Source col LINEAR: global sTs rows are pre-swizzled, so LDS content ends
  // up swizzled and the frag read deswizzles with fsw.
  const int sd = tid >> 2;
  const int scol = (tid & 3) * 8;
  const int psw = (prow & 3) << 3;
  const int fsw = (l16 & 3) << 3;

#define STAGE_PV(t, buf)                                                       \
  {                                                                            \
    _Pragma("unroll") for (int i = 0; i < 4; ++i) {                            \
      int d = i * 128 + sd;                                                    \
      __builtin_amdgcn_global_load_lds(                                        \
          (const AS1 void*)(Bz + (size_t)d * 2048 + (t) * 32 + scol),          \
          (AS3 void*)(&Bsl[buf][i * 4096 + tid * 8]), 16, 0, 0);               \
    }                                                                          \
  }

  floatx4 acc[2][4] = {};

  // ---- prologue: tile 63 -> buf 0; raw(62) prefetch in flight
  short2e rv = *(const short2e*)(rawrow + 63 * 32 + pkc);
  STAGE_PV(63, 0);
  __builtin_amdgcn_sched_barrier(0);
  {
    float p0 = __expf(h2f((unsigned short)rv[0]) - fm) * inv;
    float p1 = __expf(h2f((unsigned short)rv[1]) - fm) * inv;
    floatx2 pw = {p0, p1};
    *(floatx2*)(prowp + 63 * 32 + pkc) = pw;
    unsigned int pb = (unsigned int)f2u(p0) | ((unsigned int)f2u(p1) << 16);
    *(unsigned int*)&Pl[0][prow * 32 + (pkc ^ psw)] = pb;
  }
  short2e rvn = *(const short2e*)(rawrow + 62 * 32 + pkc);
  asm volatile("s_waitcnt lgkmcnt(0)" ::: "memory");
  asm volatile("s_waitcnt vmcnt(2)" ::: "memory");  // stage(63) done; [st,raw] left
  __builtin_amdgcn_sched_barrier(0);
  __builtin_amdgcn_s_barrier();
  __builtin_amdgcn_sched_barrier(0);

  for (int t = 63; t >= 0; --t) {
    const int cur = (63 - t) & 1, nxt = cur ^ 1;
    if (t > 0) STAGE_PV(t - 1, nxt);
    __builtin_amdgcn_sched_barrier(0);
    // frag ds_reads for tile t
    short8 af[2], bf[4];
#pragma unroll
    for (int m = 0; m < 2; ++m)
      af[m] = *(const short8*)&Pl[cur][(m * 16 + l16) * 32 + (lh * 8 ^ fsw)];
#pragma unroll
    for (int n = 0; n < 4; ++n)
      bf[n] = *(const short8*)&Bsl[cur][(w * 64 + n * 16 + l16) * 32 + (lh * 8 ^ fsw)];
    // normalize tile t-1 (overlaps MFMA window) + p store + raw(t-2) prefetch
    short2e rv2 = rvn;
    if (t > 0) {
      float p0 = __expf(h2f((unsigned short)rvn[0]) - fm) * inv;
      float p1 = __expf(h2f((unsigned short)rvn[1]) - fm) * inv;
      floatx2 pw = {p0, p1};
      *(floatx2*)(prowp + (t - 1) * 32 + pkc) = pw;
      if (t >= 2) rv2 = *(const short2e*)(rawrow + (t - 2) * 32 + pkc);
      unsigned int pb = (unsigned int)f2u(p0) | ((unsigned int)f2u(p1) << 16);
      *(unsigned int*)&Pl[nxt][prow * 32 + (pkc ^ psw)] = pb;
    }
    // MFMA on tile t
    __builtin_amdgcn_s_setprio(1);
#pragma unroll
    for (int m = 0; m < 2; ++m)
#pragma unroll
      for (int n = 0; n < 4; ++n)
        acc[m][n] = __builtin_amdgcn_mfma_f32_16x16x32_bf16(af[m], bf[n], acc[m][n], 0, 0, 0);
    __builtin_amdgcn_s_setprio(0);
    // tile end: Pl[nxt] write + frag reads drained; stage(t-1) retired.
    asm volatile("s_waitcnt lgkmcnt(0)" ::: "memory");
    if (t >= 2)
      asm volatile("s_waitcnt vmcnt(2)" ::: "memory");  // leaves [st, rv2]
    else if (t == 1)
      asm volatile("s_waitcnt vmcnt(1)" ::: "memory");  // leaves [st]
    __builtin_amdgcn_sched_barrier(0);
    if (t > 0) {
      __builtin_amdgcn_s_barrier();
      __builtin_amdgcn_sched_barrier(0);
    }
    rvn = rv2;
  }

  // epilogue: pre (bf16, linear)
  unsigned short* preB = pre + qrow0 * 512;
#pragma unroll
  for (int m = 0; m < 2; ++m)
#pragma unroll
    for (int n = 0; n < 4; ++n) {
      int row = m * 16 + lh * 4;
      int col = w * 64 + n * 16 + l16;
#pragma unroll
      for (int j = 0; j < 4; ++j)
        preB[(size_t)(row + j) * 512 + col] = f2u(acc[m][n][j]);
    }
#undef STAGE_PV
}

// ---------------------------------------------------------------------------
extern "C" void kernel_launch(void* const* d_in, const int* in_sizes, int n_in,
                              void* d_out, int out_size, void* d_ws, size_t ws_size,
                              hipStream_t stream) {
  const float* q = (const float*)d_in[0];      // [8,2048,512]
  const float* s = (const float*)d_in[1];      // [8,2048,512]
  const int* mask = (const int*)d_in[2];       // [8,1,2048]
  const float* w = (const float*)d_in[3];      // [512,512]
  const float* out_w = (const float*)d_in[4];  // [512,512]
  const float* out_b = (const float*)d_in[5];  // [512]

  float* attn_w = (float*)d_out;                              // [8,2048,2048]
  float* attn_out = (float*)d_out + (size_t)8 * 2048 * 2048;  // [8,2048,512]

  char* ws = (char*)d_ws;
  const size_t MB = 1024 * 1024;
  unsigned short* qw  = (unsigned short*)(ws);            // [16384,512] bf16
  unsigned short* sN  = (unsigned short*)(ws + 17 * MB);  // [8,2048,512] bf16
  unsigned short* sTs = (unsigned short*)(ws + 34 * MB);  // [8,512,2048] swz3
  unsigned short* pre = (unsigned short*)(ws + 51 * MB);  // [16384,512] bf16
  float2* statp       = (float2*)(ws + 51 * MB);          // [16384,32] (overlays pre)
  unsigned short* wT  = (unsigned short*)(ws + 68 * MB);  // [512,512] w^T
  unsigned short* owN = (unsigned short*)(ws + 68 * MB + 512 * 1024);
  float2* fstat       = (float2*)(ws + 69 * MB);          // [16384]

  dim3 tb(32, 8);
  cast_nt<3><<<dim3(16, 64, 8), tb, 0, stream>>>(s, sN, sTs, 2048, 512);
  cast_nt<0><<<dim3(16, 16, 1), tb, 0, stream>>>(w, nullptr, wT, 512, 512);
  cast_nt<0><<<dim3(16, 16, 1), tb, 0, stream>>>(out_w, owN, nullptr, 512, 512);

  // GEMM1: qw = q @ w (bf16 linear)
  gemm_bt<1, 0><<<dim3(4, 128, 1), 256, 0, stream>>>(q, wT, qw, nullptr, 512, 512);

  // scores + mask + partial stats; raw fp16 packed into attn_w rows
  gemm_sc<<<dim3(16, 16, 8), 256, 0, stream>>>(qw, sN, mask, attn_w, statp);

  // stats combine
  finalize_stats<<<64, 256, 0, stream>>>(statp, fstat);

  // in-place normalize + PV (32-row strips, 2 blocks/CU, single-barrier)
  pv_norm<<<512, 512, 0, stream>>>(attn_w, sTs, fstat, pre);

  // GEMM4: attn_out = pre @ out_w^T + out_b
  gemm_bt<0, 2><<<dim3(4, 128, 1), 256, 0, stream>>>(pre, owN, attn_out, out_b, 512, 512);

  (void)in_sizes; (void)n_in; (void)out_size; (void)ws_size;
}

// Round 16
// 206.618 us; speedup vs baseline: 1.1604x; 1.1220x over previous
//
#include <hip/hip_runtime.h>

// MultiplicativeAttention: B=8, QL=SL=2048, QD=SD=OD=512
//   qw = q@w; scores = qw@s^T (mask -> -1e10); attn_w = softmax(scores);
//   attn_out = (attn_w @ s) @ out_w^T + out_b
// Outputs (fp32, concat): attn_w [8*2048*2048], attn_out [8*2048*512]
//
// R16 = exact revert to R12 (best measured, 207.0us):
//   gemm_sc: triple-buffered counted-vmcnt(8) K-loop
//   pv_norm: 64-row strips, single-barrier pipelined, mask-7 swizzle
//   (R13/R15's 32-row pv_norm re-tile measured WORSE: 96us, 6.3M bank
//    conflicts, thin-barrier overhead — reverted per pre-committed fallback.)

#define NEG_FILL -60000.0f  // fp16-exact mask fill; exp(NEG_FILL - m) == 0

#define AS1 __attribute__((address_space(1)))
#define AS3 __attribute__((address_space(3)))

typedef __attribute__((ext_vector_type(8))) short short8;   // 8 bf16/fp16
typedef __attribute__((ext_vector_type(4))) float floatx4;  // MFMA acc

__device__ __forceinline__ unsigned short f2u(float x) {  // f32 -> bf16 RNE
  unsigned int u = __float_as_uint(x);
  unsigned int r = (u + 0x7fffu + ((u >> 16) & 1u)) >> 16;
  return (unsigned short)r;
}
__device__ __forceinline__ unsigned short f2h(float x) {  // f32 -> fp16 bits
  _Float16 h = (_Float16)x;
  return __builtin_bit_cast(unsigned short, h);
}
__device__ __forceinline__ float h2f(unsigned short u) {  // fp16 bits -> f32
  _Float16 h = __builtin_bit_cast(_Float16, u);
  return (float)h;
}

// ---------------------------------------------------------------------------
// cast fp32 [R][C] -> bf16 copy (dN) and/or transpose (dT); SWT bakes the
// XOR-swizzle into dT's row layout: dT[d][k ^ ((d&7)<<3)] = src[k][d]
template <int SWT>
__global__ void cast_nt(const float* __restrict__ src,
                        unsigned short* __restrict__ dN,
                        unsigned short* __restrict__ dT, int R, int C) {
  __shared__ unsigned short t[32][33];
  const int b = blockIdx.z;
  const size_t boff = (size_t)b * R * C;
  const int r0 = blockIdx.y * 32, c0 = blockIdx.x * 32;
  const int tx = threadIdx.x;
  for (int i = threadIdx.y; i < 32; i += 8) {
    unsigned short u = f2u(src[boff + (size_t)(r0 + i) * C + c0 + tx]);
    t[i][tx] = u;
    if (dN) dN[boff + (size_t)(r0 + i) * C + c0 + tx] = u;
  }
  __syncthreads();
  if (dT)
    for (int i = threadIdx.y; i < 32; i += 8) {
      int d = c0 + i;  // dT row
      int k = r0 + tx; // dT col
      int el = SWT ? (k ^ ((d & 7) << 3)) : k;
      dT[boff + (size_t)d * R + el] = t[tx][i];
    }
}

// ---------------------------------------------------------------------------
// Generic GEMM: C[m][n] = sum_k A[m][k]*Bt[n][k]. 128x128 tile, BK=32, 4 waves.
// AF32: A fp32 reg-staged; else bf16 via global_load_lds.
// OUT_MODE: 0 = bf16 linear out; 2 = fp32 + bias
template <int AF32, int OUT_MODE>
__global__ __launch_bounds__(256) void gemm_bt(
    const void* __restrict__ A_, const unsigned short* __restrict__ Bt_,
    void* __restrict__ C_, const float* __restrict__ bias, int N, int K) {
  __shared__ unsigned short As[128 * 32];
  __shared__ unsigned short Bs[128 * 32];

  const int tid = threadIdx.x;
  const int lane = tid & 63, wave = tid >> 6;
  const int wr = wave >> 1, wc = wave & 1;
  const int l16 = lane & 15, lh = lane >> 4;
  const int m0 = blockIdx.y * 128, n0 = blockIdx.x * 128;
  const unsigned short* Bt = Bt_;

  floatx4 acc[4][4] = {};

  for (int k0 = 0; k0 < K; k0 += 32) {
    float4 av[4];
    if constexpr (AF32) {
      const float* A = (const float*)A_;
#pragma unroll
      for (int i = 0; i < 4; ++i) {
        int e = (i * 256 + tid) * 4;
        int row = e >> 5, kk = e & 31;
        av[i] = *(const float4*)(A + (size_t)(m0 + row) * K + k0 + kk);
      }
    }
    __syncthreads();
    if constexpr (AF32) {
#pragma unroll
      for (int i = 0; i < 4; ++i) {
        int e = (i * 256 + tid) * 4;
        unsigned short b4[4] = {f2u(av[i].x), f2u(av[i].y), f2u(av[i].z), f2u(av[i].w)};
        *(uint2*)&As[e] = *(uint2*)b4;
      }
    } else {
      const unsigned short* A = (const unsigned short*)A_;
#pragma unroll
      for (int i = 0; i < 2; ++i) {
        int chunk = i * 4 + wave;
        int e = chunk * 512 + lane * 8;
        int row = e >> 5, kk = e & 31;
        __builtin_amdgcn_global_load_lds(
            (const AS1 void*)(A + (size_t)(m0 + row) * K + k0 + kk),
            (AS3 void*)(As + chunk * 512), 16, 0, 0);
      }
    }
#pragma unroll
    for (int i = 0; i < 2; ++i) {
      int chunk = i * 4 + wave;
      int e = chunk * 512 + lane * 8;
      int row = e >> 5, kk = e & 31;
      __builtin_amdgcn_global_load_lds(
          (const AS1 void*)(Bt + (size_t)(n0 + row) * K + k0 + kk),
          (AS3 void*)(Bs + chunk * 512), 16, 0, 0);
    }
    __syncthreads();

    short8 af[4], bfr[4];
#pragma unroll
    for (int m = 0; m < 4; ++m)
      af[m] = *(const short8*)&As[(wr * 64 + m * 16 + l16) * 32 + lh * 8];
#pragma unroll
    for (int n = 0; n < 4; ++n)
      bfr[n] = *(const short8*)&Bs[(wc * 64 + n * 16 + l16) * 32 + lh * 8];
#pragma unroll
    for (int m = 0; m < 4; ++m)
#pragma unroll
      for (int n = 0; n < 4; ++n)
        acc[m][n] = __builtin_amdgcn_mfma_f32_16x16x32_bf16(af[m], bfr[n], acc[m][n], 0, 0, 0);
  }

  const int rbase = m0 + wr * 64, cbase = n0 + wc * 64;
  if constexpr (OUT_MODE == 0) {
    unsigned short* C = (unsigned short*)C_;
#pragma unroll
    for (int m = 0; m < 4; ++m)
#pragma unroll
      for (int n = 0; n < 4; ++n) {
        int row = rbase + m * 16 + lh * 4;
        int col = cbase + n * 16 + l16;
#pragma unroll
        for (int j = 0; j < 4; ++j)
          C[(size_t)(row + j) * N + col] = f2u(acc[m][n][j]);
      }
  } else {
    float* C = (float*)C_;
#pragma unroll
    for (int n = 0; n < 4; ++n) {
      int col = cbase + n * 16 + l16;
      float bv = bias[col];
#pragma unroll
      for (int m = 0; m < 4; ++m) {
        int row = rbase + m * 16 + lh * 4;
#pragma unroll
        for (int j = 0; j < 4; ++j)
          C[(size_t)(row + j) * N + col] = acc[m][n][j] + bv;
      }
    }
  }
}

// ---------------------------------------------------------------------------
// Scores + mask + partial softmax stats. 128x128 tile, BK=32, 4 waves.
// K-loop: TRIPLE-buffered As/Bs, 3-deep prefetch, counted vmcnt(8) — each
// stage gets two full iteration windows before its wait; no mid-loop drains.
__global__ __launch_bounds__(256) void gemm_sc(
    const unsigned short* __restrict__ qw,   // [16384][512] bf16
    const unsigned short* __restrict__ sN,   // [8][2048][512] bf16
    const int* __restrict__ maskg,           // [8][2048]
    float* __restrict__ attw,                // [16384][2048] fp32 slots
    float2* __restrict__ statp) {            // [16384][32]
  __shared__ unsigned short As[3][128 * 32];  // 3 x 8 KB
  __shared__ unsigned short Bs[3][128 * 32];  // 3 x 8 KB -> 48 KB total

  const int tid = threadIdx.x;
  const int lane = tid & 63, wave = tid >> 6;
  const int wr = wave >> 1, wc = wave & 1;
  const int l16 = lane & 15, lh = lane >> 4;
  const int z = blockIdx.z;
  const int m0 = blockIdx.y * 128, n0 = blockIdx.x * 128;
  const unsigned short* Ab = qw + ((size_t)z * 2048 + m0) * 512;
  const unsigned short* Bb = sN + ((size_t)z * 2048 + n0) * 512;

  const int chunk0 = wave, chunk1 = 4 + wave;
  const int e0 = chunk0 * 512 + lane * 8, e1 = chunk1 * 512 + lane * 8;
  const int row0 = e0 >> 5, kk0 = e0 & 31;
  const int row1 = e1 >> 5, kk1 = e1 & 31;

#define STAGE_SC(t, buf)                                                      \
  {                                                                           \
    const int k0_ = (t) * 32;                                                 \
    __builtin_amdgcn_global_load_lds(                                         \
        (const AS1 void*)(Ab + (size_t)row0 * 512 + k0_ + kk0),               \
        (AS3 void*)(&As[buf][chunk0 * 512]), 16, 0, 0);                       \
    __builtin_amdgcn_global_load_lds(                                         \
        (const AS1 void*)(Bb + (size_t)row0 * 512 + k0_ + kk0),               \
        (AS3 void*)(&Bs[buf][chunk0 * 512]), 16, 0, 0);                       \
    __builtin_amdgcn_global_load_lds(                                         \
        (const AS1 void*)(Ab + (size_t)row1 * 512 + k0_ + kk1),               \
        (AS3 void*)(&As[buf][chunk1 * 512]), 16, 0, 0);                       \
    __builtin_amdgcn_global_load_lds(                                         \
        (const AS1 void*)(Bb + (size_t)row1 * 512 + k0_ + kk1),               \
        (AS3 void*)(&Bs[buf][chunk1 * 512]), 16, 0, 0);                       \
  }

  floatx4 acc[4][4] = {};

  STAGE_SC(0, 0);
  STAGE_SC(1, 1);
  for (int t = 0; t < 16; ++t) {
    const int cur = t % 3;
    if (t + 2 < 16) STAGE_SC(t + 2, (t + 2) % 3);
    __builtin_amdgcn_sched_barrier(0);
    if (t + 2 < 16)
      asm volatile("s_waitcnt vmcnt(8)" ::: "memory");
    else if (t + 1 < 16)
      asm volatile("s_waitcnt vmcnt(4)" ::: "memory");
    else
      asm volatile("s_waitcnt vmcnt(0)" ::: "memory");
    __builtin_amdgcn_s_barrier();
    __builtin_amdgcn_sched_barrier(0);

    short8 af[4], bfr[4];
#pragma unroll
    for (int m = 0; m < 4; ++m)
      af[m] = *(const short8*)&As[cur][(wr * 64 + m * 16 + l16) * 32 + lh * 8];
#pragma unroll
    for (int n = 0; n < 4; ++n)
      bfr[n] = *(const short8*)&Bs[cur][(wc * 64 + n * 16 + l16) * 32 + lh * 8];
#pragma unroll
    for (int m = 0; m < 4; ++m)
#pragma unroll
      for (int n = 0; n < 4; ++n)
        acc[m][n] = __builtin_amdgcn_mfma_f32_16x16x32_bf16(af[m], bfr[n], acc[m][n], 0, 0, 0);

    asm volatile("s_waitcnt lgkmcnt(0)" ::: "memory");
    __builtin_amdgcn_sched_barrier(0);
    __builtin_amdgcn_s_barrier();
  }
#undef STAGE_SC

  // epilogue: mask, raw fp16 write, partial stats
  bool keep[4];
#pragma unroll
  for (int n = 0; n < 4; ++n)
    keep[n] = maskg[z * 2048 + n0 + wc * 64 + n * 16 + l16] != 0;
#pragma unroll
  for (int m = 0; m < 4; ++m)
#pragma unroll
    for (int n = 0; n < 4; ++n)
      if (!keep[n]) {
        floatx4 f = {NEG_FILL, NEG_FILL, NEG_FILL, NEG_FILL};
        acc[m][n] = f;
      }

#pragma unroll
  for (int m = 0; m < 4; ++m)
#pragma unroll
    for (int j = 0; j < 4; ++j) {
      const int lrow = m0 + wr * 64 + m * 16 + lh * 4 + j;
      const size_t grow = (size_t)z * 2048 + lrow;
      unsigned short* rawrow = (unsigned short*)(attw + grow * 2048);
#pragma unroll
      for (int n = 0; n < 4; ++n)
        rawrow[n0 + wc * 64 + n * 16 + l16] = f2h(acc[m][n][j]);
      float tm = fmaxf(fmaxf(acc[m][0][j], acc[m][1][j]),
                       fmaxf(acc[m][2][j], acc[m][3][j]));
#pragma unroll
      for (int o = 1; o < 16; o <<= 1) tm = fmaxf(tm, __shfl_xor(tm, o));
      float es = __expf(acc[m][0][j] - tm) + __expf(acc[m][1][j] - tm) +
                 __expf(acc[m][2][j] - tm) + __expf(acc[m][3][j] - tm);
#pragma unroll
      for (int o = 1; o < 16; o <<= 1) es += __shfl_xor(es, o);
      if (l16 == 0) {
        float2 st = {tm, es};
        statp[grow * 32 + blockIdx.x * 2 + wc] = st;
      }
    }
}

// ---------------------------------------------------------------------------
// Combine 32 partials per row -> (max, 1/sum). 16384 rows.
__global__ __launch_bounds__(256) void finalize_stats(
    const float2* __restrict__ statp, float2* __restrict__ fstat) {
  const int r = blockIdx.x * 256 + threadIdx.x;
  const float2* p = statp + (size_t)r * 32;
  float fm = -3.4e38f;
#pragma unroll
  for (int i = 0; i < 32; ++i) fm = fmaxf(fm, p[i].x);
  float fs = 0.f;
#pragma unroll
  for (int i = 0; i < 32; ++i) fs += p[i].y * __expf(p[i].x - fm);
  float2 o = {fm, 1.0f / fs};
  fstat[r] = o;
}

// ---------------------------------------------------------------------------
// Normalize + PV. Block = 64 q-rows x N=512, 8 waves (wave w owns cols
// w*64..+64). Descending k-tiles: fp32 p-writes never clobber unread fp16 raw.
// Single-barrier/tile pipeline: dbuf Bsl+Pl; queue invariant [st,st,raw] ->
// vmcnt(3); never a drain in the main loop.
__global__ __launch_bounds__(512) void pv_norm(
    float* __restrict__ attw,                 // rows: fp16 raw -> fp32 p
    const unsigned short* __restrict__ sTs,   // [8][512][2048] swizzled (mask 7)
    const float2* __restrict__ fstat,         // [16384] (max, 1/sum)
    unsigned short* __restrict__ pre) {       // [16384][512] bf16
  __shared__ unsigned short Bsl[2][512 * 64];  // 128 KB
  __shared__ unsigned short Pl[2][64 * 64];    // 16 KB -> 144 KB total
  const int tid = threadIdx.x, lane = tid & 63, w = tid >> 6;
  const int l16 = lane & 15, lh = lane >> 4;
  const int z = blockIdx.x & 7, ms = blockIdx.x >> 3;  // batch -> XCD pinning
  const size_t qrow0 = (size_t)z * 2048 + ms * 64;
  const unsigned short* Bz = sTs + (size_t)z * 512 * 2048;
  float* attwB = attw + qrow0 * 2048;
  const int prow = tid >> 3, pkc = (tid & 7) * 8;
  const unsigned short* rawrow = (const unsigned short*)(attwB + (size_t)prow * 2048);
  float* prowp = attwB + (size_t)prow * 2048;
  const float2 st0 = fstat[qrow0 + prow];
  const float fm = st0.x, inv = st0.y;
  const int bd = w * 8 + (lane >> 3);
  const int bkk = (lane & 7) * 8;
  const int psw = (prow & 7) << 3;
  const int fsw = (l16 & 7) << 3;

  floatx4 acc[4][4] = {};

  // ---- prologue: tile 31 -> buf 0; raw(30) prefetch in flight
  short8 rv = *(const short8*)(rawrow + 31 * 64 + pkc);  // Q=[rv31]
#pragma unroll
  for (int i = 0; i < 8; ++i) {
    int d = i * 64 + bd;
    __builtin_amdgcn_global_load_lds(
        (const AS1 void*)(Bz + (size_t)d * 2048 + 31 * 64 + bkk),
        (AS3 void*)(&Bsl[0][(size_t)d * 64 + bkk]), 16, 0, 0);
  }
  __builtin_amdgcn_sched_barrier(0);  // pin glds queue position
  {
    float p[8];
#pragma unroll
    for (int e = 0; e < 8; ++e)
      p[e] = __expf(h2f((unsigned short)rv[e]) - fm) * inv;  // waits rv: vmcnt(8)
    float4 lo = {p[0], p[1], p[2], p[3]};
    float4 hi = {p[4], p[5], p[6], p[7]};
    *(float4*)(prowp + 31 * 64 + pkc) = lo;
    *(float4*)(prowp + 31 * 64 + pkc + 4) = hi;
    short8 pb;
#pragma unroll
    for (int e = 0; e < 8; ++e) pb[e] = (short)f2u(p[e]);
    *(short8*)&Pl[0][prow * 64 + (pkc ^ psw)] = pb;
  }
  short8 rvn = *(const short8*)(rawrow + 30 * 64 + pkc);  // Q=[g8,st,st,rv30]
  asm volatile("s_waitcnt lgkmcnt(0)" ::: "memory");
  asm volatile("s_waitcnt vmcnt(3)" ::: "memory");  // Q=[st,st,rv30]
  __builtin_amdgcn_sched_barrier(0);
  __builtin_amdgcn_s_barrier();
  __builtin_amdgcn_sched_barrier(0);

  for (int t = 31; t >= 0; --t) {
    const int cur = (31 - t) & 1, nxt = cur ^ 1;
    // stage B(t-1) first (queue: oldest after carried [st,st,rv])
    if (t > 0) {
#pragma unroll
      for (int i = 0; i < 8; ++i) {
        int d = i * 64 + bd;
        __builtin_amdgcn_global_load_lds(
            (const AS1 void*)(Bz + (size_t)d * 2048 + (t - 1) * 64 + bkk),
            (AS3 void*)(&Bsl[nxt][(size_t)d * 64 + bkk]), 16, 0, 0);
      }
    }
    __builtin_amdgcn_sched_barrier(0);  // pin glds before stores/loads below
    // frag ds_reads for tile t
    short8 af[4][2], bf2[4][2];
#pragma unroll
    for (int m = 0; m < 4; ++m)
#pragma unroll
      for (int ks = 0; ks < 2; ++ks)
        af[m][ks] = *(const short8*)&Pl[cur][(m * 16 + l16) * 64 + ((ks * 32 + lh * 8) ^ fsw)];
#pragma unroll
    for (int n = 0; n < 4; ++n)
#pragma unroll
      for (int ks = 0; ks < 2; ++ks)
        bf2[n][ks] = *(const short8*)&Bsl[cur][(w * 64 + n * 16 + l16) * 64 +
                                               ((ks * 32 + lh * 8) ^ fsw)];
    // normalize tile t-1 (VALU, overlaps MFMA window) + p stores + raw(t-2)
    short8 rv2 = rvn;
    if (t > 0) {
      float p[8];
#pragma unroll
      for (int e = 0; e < 8; ++e)
        p[e] = __expf(h2f((unsigned short)rvn[e]) - fm) * inv;  // vmcnt(8) wait
      float4 lo = {p[0], p[1], p[2], p[3]};
      float4 hi = {p[4], p[5], p[6], p[7]};
      *(float4*)(prowp + (t - 1) * 64 + pkc) = lo;
      *(float4*)(prowp + (t - 1) * 64 + pkc + 4) = hi;
      if (t >= 2) rv2 = *(const short8*)(rawrow + (t - 2) * 64 + pkc);
      short8 pb;
#pragma unroll
      for (int e = 0; e < 8; ++e) pb[e] = (short)f2u(p[e]);
      *(short8*)&Pl[nxt][prow * 64 + (pkc ^ psw)] = pb;
    }
    // MFMA on tile t
#pragma unroll
    for (int ks = 0; ks < 2; ++ks)
#pragma unroll
      for (int m = 0; m < 4; ++m)
#pragma unroll
        for (int n = 0; n < 4; ++n)
          acc[m][n] = __builtin_amdgcn_mfma_f32_16x16x32_bf16(af[m][ks], bf2[n][ks],
                                                              acc[m][n], 0, 0, 0);
    // tile end: Pl[nxt] write + frag reads drained; B(t-1) glds retired.
    asm volatile("s_waitcnt lgkmcnt(0)" ::: "memory");
    if (t >= 2)
      asm volatile("s_waitcnt vmcnt(3)" ::: "memory");  // leaves [st,st,rv2]
    else if (t == 1)
      asm volatile("s_waitcnt vmcnt(2)" ::: "memory");  // leaves [st,st]
    __builtin_amdgcn_sched_barrier(0);
    if (t > 0) {
      __builtin_amdgcn_s_barrier();
      __builtin_amdgcn_sched_barrier(0);
    }
    rvn = rv2;
  }

  // epilogue: pre (bf16, linear)
  unsigned short* preB = pre + qrow0 * 512;
#pragma unroll
  for (int m = 0; m < 4; ++m)
#pragma unroll
    for (int n = 0; n < 4; ++n) {
      int row = m * 16 + lh * 4;
      int col = w * 64 + n * 16 + l16;
#pragma unroll
      for (int j = 0; j < 4; ++j)
        preB[(size_t)(row + j) * 512 + col] = f2u(acc[m][n][j]);
    }
}

// ---------------------------------------------------------------------------
extern "C" void kernel_launch(void* const* d_in, const int* in_sizes, int n_in,
                              void* d_out, int out_size, void* d_ws, size_t ws_size,
                              hipStream_t stream) {
  const float* q = (const float*)d_in[0];      // [8,2048,512]
  const float* s = (const float*)d_in[1];      // [8,2048,512]
  const int* mask = (const int*)d_in[2];       // [8,1,2048]
  const float* w = (const float*)d_in[3];      // [512,512]
  const float* out_w = (const float*)d_in[4];  // [512,512]
  const float* out_b = (const float*)d_in[5];  // [512]

  float* attn_w = (float*)d_out;                              // [8,2048,2048]
  float* attn_out = (float*)d_out + (size_t)8 * 2048 * 2048;  // [8,2048,512]

  char* ws = (char*)d_ws;
  const size_t MB = 1024 * 1024;
  unsigned short* qw  = (unsigned short*)(ws);            // [16384,512] bf16
  unsigned short* sN  = (unsigned short*)(ws + 17 * MB);  // [8,2048,512] bf16
  unsigned short* sTs = (unsigned short*)(ws + 34 * MB);  // [8,512,2048] swizzled
  unsigned short* pre = (unsigned short*)(ws + 51 * MB);  // [16384,512] bf16
  float2* statp       = (float2*)(ws + 51 * MB);          // [16384,32] (overlays pre)
  unsigned short* wT  = (unsigned short*)(ws + 68 * MB);  // [512,512] w^T
  unsigned short* owN = (unsigned short*)(ws + 68 * MB + 512 * 1024);
  float2* fstat       = (float2*)(ws + 69 * MB);          // [16384]

  dim3 tb(32, 8);
  cast_nt<1><<<dim3(16, 64, 8), tb, 0, stream>>>(s, sN, sTs, 2048, 512);
  cast_nt<0><<<dim3(16, 16, 1), tb, 0, stream>>>(w, nullptr, wT, 512, 512);
  cast_nt<0><<<dim3(16, 16, 1), tb, 0, stream>>>(out_w, owN, nullptr, 512, 512);

  // GEMM1: qw = q @ w (bf16 linear)
  gemm_bt<1, 0><<<dim3(4, 128, 1), 256, 0, stream>>>(q, wT, qw, nullptr, 512, 512);

  // scores + mask + partial stats; raw fp16 packed into attn_w rows
  gemm_sc<<<dim3(16, 16, 8), 256, 0, stream>>>(qw, sN, mask, attn_w, statp);

  // stats combine
  finalize_stats<<<64, 256, 0, stream>>>(statp, fstat);

  // in-place normalize + PV (single-barrier pipelined)
  pv_norm<<<256, 512, 0, stream>>>(attn_w, sTs, fstat, pre);

  // GEMM4: attn_out = pre @ out_w^T + out_b
  gemm_bt<0, 2><<<dim3(4, 128, 1), 256, 0, stream>>>(pre, owN, attn_out, out_b, 512, 512);

  (void)in_sizes; (void)n_in; (void)out_size; (void)ws_size;
}